// Round 6
// baseline (143.962 us; speedup 1.0000x reference)
//
#include <hip/hip_runtime.h>
#include <stdint.h>

#define IN_SIZE 224
#define KER 5
#define IN_CH 16
#define OUT_CH 64
#define NH 220
#define NB_TILES (NH * NH)       // 48400
#define XCH (IN_SIZE * IN_SIZE)  // 50176
#define OUT_PLANE NB_TILES
#define KP2 51200                // padded K for gemm
#define XS 52224                 // per-plane stride in shifted-x copies
#define LR_OVER_NB ((float)(0.005 / 48400.0))
#define GAMMA_F 0.99f
#define ONE_MINUS_GAMMA 0.01f
#define EPS_F 0.01f

#define NCHUNK 64
#define CK 800                   // 25 steps of BK=32
#define PSTRIDE (64 * 512)

typedef __attribute__((ext_vector_type(8))) short short8;
typedef __attribute__((ext_vector_type(4))) float floatx4;

__device__ inline uint16_t f2bf(float f) {
    uint32_t u = __float_as_uint(f);
    return (uint16_t)((u + 0x7FFFu + ((u >> 16) & 1u)) >> 16);
}
__device__ inline float bf2f(uint16_t h) { return __uint_as_float((uint32_t)h << 16); }

// ---- Kernel 1: conv MFMA (B staged from x directly, hi/lo split in-kernel,
// XOR-swizzled LDS; W fragments built per-thread IN REGISTERS from W — the
// old prepa kernel is deleted) + inhibition; prepB fused.
// blocks 0..769: conv; blocks 770..2809: prepB (independent memory work) ----
__global__ __launch_bounds__(256) void conv_prep_kernel(const float* __restrict__ W,
                                                        float* __restrict__ out,
                                                        uint16_t* __restrict__ yb,
                                                        const float* __restrict__ x,
                                                        uint16_t* __restrict__ xs,
                                                        uint16_t* __restrict__ ones,
                                                        float* __restrict__ msum) {
    if (blockIdx.x >= 770) {  // ---- prepB ----
        int t = (blockIdx.x - 770) * 256 + threadIdx.x;
        const int perq8 = XS / 8;  // 6528
        // xs shifted-copy build, 8 bf16 (16 B) per thread: t covers 5*16*6528 = 522240 exactly
        {
            int kj = t / (16 * perq8);
            int rem = t - kj * (16 * perq8);
            int c = rem / perq8;
            int q = (rem - c * perq8) * 8;
            int base = c * XCH;
            uint32_t d[4];
#pragma unroll
            for (int p = 0; p < 4; p++) {
                int i0 = q + kj + 2 * p;
                int i1 = i0 + 1;
                uint16_t h0 = f2bf(x[base + (i0 < XCH ? i0 : XCH - 1)]);
                uint16_t h1 = f2bf(x[base + (i1 < XCH ? i1 : XCH - 1)]);
                d[p] = (uint32_t)h0 | ((uint32_t)h1 << 16);
            }
            *(uint4*)(xs + (kj * 16 + c) * XS + q) = make_uint4(d[0], d[1], d[2], d[3]);
        }
        ushort4 z = {0, 0, 0, 0};
        if (t < 64 * 480) {  // zero yb K-tail [49280,51200)
            int r = t / 480, q = (t - r * 480) * 4;
            *(ushort4*)(yb + r * KP2 + 49280 + q) = z;
        }
        if (t < 64 * 220) {  // zero yb j-pad cols 220..223
            int o = t / 220, i = t - o * 220;
            *(ushort4*)(yb + o * KP2 + i * 224 + 220) = z;
        }
        if (t < 12816) {  // bf16 ones (51264 entries)
            ushort4 o1 = {0x3F80, 0x3F80, 0x3F80, 0x3F80};
            ((ushort4*)ones)[t] = o1;
        }
        if (t < 8192) {  // zero Msum (64*512 floats) for gemm's atomic accumulate
            float4 z4 = make_float4(0.f, 0.f, 0.f, 0.f);
            ((float4*)msum)[t] = z4;
        }
        return;
    }

    const int lane = threadIdx.x & 63;
    const int w = threadIdx.x >> 6;
    const int l15 = lane & 15;
    const int quad = lane >> 4;
    const int P0 = blockIdx.x * 64;
    const int chalf = quad & 1;   // which 8-channel half this quad reads
    const int sq = quad >> 1;

    // ---- W fragments in registers (replaces prepa + wrh/wrl global loads).
    // Old generator: for fragment elem j at (t,w,lane): k=quad*8+j, s=k>>4=quad>>1,
    // c=k&15=(quad&1)*8+j, oc=16w+l15, tap=2t+s, v=(tap<25)?W[oc*400+c*25+tap]:0.
    // Both loops fully unrolled -> compile-time indexing, stays in VGPRs.
    const int s_tap = quad >> 1;
    const float* wbase = W + (16 * w + l15) * 400 + ((quad & 1) * 8) * 25 + s_tap;
    short8 ahr[13], alr[13];
#pragma unroll
    for (int t = 0; t < 13; t++) {
        const bool dead = (t == 12);  // tap=25 iff t==12 && s_tap==1
#pragma unroll
        for (int j = 0; j < 8; j++) {
            // clamp address in the dead case so the load stays in-bounds
            int off = (dead && s_tap == 1) ? 0 : (j * 25 + 2 * t);
            float v = wbase[off];
            if (dead && s_tap == 1) v = 0.f;
            uint16_t h = f2bf(v);
            ahr[t][j] = (short)h;
            alr[t][j] = (short)f2bf(v - bf2f(h));
        }
    }

    // ---- stage the block's B-window (5 strips x 68 rows x 16ch, hi+lo) in LDS,
    // built directly from x. 16B-unit index u = row*2+half XOR-swizzled with
    // ((row>>2)&1): rows differing by 4 land in different bank quads -> 2-way (free).
    __shared__ uint16_t bsh[5 * 68 * 16];  // 10.9 KB
    __shared__ uint16_t bsl[5 * 68 * 16];  // 10.9 KB
    for (int u = threadIdx.x; u < 680; u += 256) {
        int row = u >> 1;            // 0..339
        int half = u & 1;            // channel half 0/1
        int strip = row / 68;
        int rr = row - strip * 68;
        int grow = P0 + strip * 224 + rr;  // may overhang past XCH on last blocks
        bool inb = grow < XCH;
        uint32_t dh[4], dl[4];
#pragma unroll
        for (int q = 0; q < 4; q++) {
            float v0 = inb ? x[(half * 8 + 2 * q) * XCH + grow] : 0.f;
            float v1 = inb ? x[(half * 8 + 2 * q + 1) * XCH + grow] : 0.f;
            uint16_t h0 = f2bf(v0), h1 = f2bf(v1);
            uint16_t l0 = f2bf(v0 - bf2f(h0)), l1 = f2bf(v1 - bf2f(h1));
            dh[q] = (uint32_t)h0 | ((uint32_t)h1 << 16);
            dl[q] = (uint32_t)l0 | ((uint32_t)l1 << 16);
        }
        int swz = (u ^ ((row >> 2) & 1)) * 8;  // swizzled elem offset
        *(uint4*)(bsh + swz) = make_uint4(dh[0], dh[1], dh[2], dh[3]);
        *(uint4*)(bsl + swz) = make_uint4(dl[0], dl[1], dl[2], dl[3]);
    }
    __syncthreads();

    floatx4 acc[4];
#pragma unroll
    for (int g = 0; g < 4; g++) acc[g] = (floatx4){0.f, 0.f, 0.f, 0.f};

#pragma unroll
    for (int t = 0; t < 13; t++) {
        short8 ah = ahr[t];
        short8 al = alr[t];
        const int tap0 = 2 * t, tap1 = 2 * t + 1;
        const int ki0 = tap0 / 5, kj0 = tap0 % 5;
        const int ki1 = (tap1 <= 24) ? tap1 / 5 : 0;
        const int kj1 = (tap1 <= 24) ? tap1 % 5 : 0;
        const int strip = sq ? ki1 : ki0;
        const int kjv = sq ? kj1 : kj0;
#pragma unroll
        for (int g = 0; g < 4; g++) {
            int lrow = strip * 68 + 16 * g + l15 + kjv;
            int unit = lrow * 2 + chalf;
            int off = (unit ^ ((lrow >> 2) & 1)) * 8;
            short8 bh = *(const short8*)(bsh + off);
            short8 bl = *(const short8*)(bsl + off);
            acc[g] = __builtin_amdgcn_mfma_f32_16x16x32_bf16(ah, bh, acc[g], 0, 0, 0);
            acc[g] = __builtin_amdgcn_mfma_f32_16x16x32_bf16(ah, bl, acc[g], 0, 0, 0);
            acc[g] = __builtin_amdgcn_mfma_f32_16x16x32_bf16(al, bh, acc[g], 0, 0, 0);
        }
    }

    __shared__ float wmax[4][64];
    float pmax[4];
#pragma unroll
    for (int g = 0; g < 4; g++) {
        float mx = fmaxf(fmaxf(acc[g][0], acc[g][1]), fmaxf(acc[g][2], acc[g][3]));
        mx = fmaxf(mx, 0.f);
        mx = fmaxf(mx, __shfl_xor(mx, 16));
        mx = fmaxf(mx, __shfl_xor(mx, 32));
        pmax[g] = mx;
    }
    if (quad == 0) {
#pragma unroll
        for (int g = 0; g < 4; g++) wmax[w][g * 16 + l15] = pmax[g];
    }
    __syncthreads();

#pragma unroll
    for (int g = 0; g < 4; g++) {
        int P = P0 + 16 * g + l15;
        int i = P / 224;
        int j = P - i * 224;
        bool valid = j < NH;
        float mx = fmaxf(fmaxf(wmax[0][g * 16 + l15], wmax[1][g * 16 + l15]),
                         fmaxf(wmax[2][g * 16 + l15], wmax[3][g * 16 + l15]));
        float inv = 1.f / (mx + 1e-9f);
#pragma unroll
        for (int r = 0; r < 4; r++) {
            float tv = fmaxf(acc[g][r], 0.f) * inv;
            float t2 = tv * tv;
            tv = t2 * t2 * tv;
            if (valid) {
                int oc = 16 * w + quad * 4 + r;
                out[oc * OUT_PLANE + i * NH + j] = tv;
                yb[oc * KP2 + P] = f2bf(tv);
            }
        }
    }
}

// ---- Kernel 2: LDS-staged GEMM y^T @ [xf|y|1], conflict-free LDS layout,
// epilogue ATOMICALLY accumulates into Msum[64][512] (fp32, device-scope;
// 64 chunk-blocks collide per address spread over the kernel's lifetime).
// Replaces the 8.4 MB Mpart + finalize's 64-chunk scattered reduction. ----
__global__ __launch_bounds__(256) void gemm_kernel(const uint16_t* __restrict__ yb,
                                                   const uint16_t* __restrict__ xs,
                                                   const uint16_t* __restrict__ ones,
                                                   float* __restrict__ msum) {
    __shared__ uint16_t As[2][64 * 64];
    __shared__ uint16_t Bs[2][64 * 64];
    const int tid = threadIdx.x;
    const int lane = tid & 63;
    const int w = tid >> 6;
    const int l15 = lane & 15;
    const int quad = lane >> 4;
    const int b = blockIdx.x;
    const int xcd = b & 7;
    const int t8 = b >> 3;
    const int ntile = t8 & 7;
    const int chunk = xcd + 8 * (t8 >> 3);
    const int k0 = chunk * CK;

    const int sr = tid >> 2;          // staged row 0..63
    const int sq = tid & 3;           // staged K-segment 0..3
    const int sseg = sq * 8;
    const uint16_t* pa = yb + sr * KP2 + k0 + sseg;

    int n_g = ntile * 64 + sr;
    const uint16_t* pbase;
    if (n_g < 400) {
        int c = n_g / 25;
        int r = n_g - 25 * c;
        int ki = r / 5;
        int kj = r - 5 * ki;
        pbase = xs + (kj * 16 + c) * XS + ki * 224;
    } else if (n_g < 464) {
        pbase = yb + (n_g - 400) * KP2;
    } else if (n_g == 464) {
        pbase = ones;
    } else {
        pbase = yb;  // dead column
    }
    const uint16_t* pb = pbase + k0 + sseg;

    const int woff = sr * 64 + ((2 * sq + sr) & 7) * 8;    // swizzled write offset
    const int ru = ((2 * quad + l15) & 7) * 8;             // swizzled read unit offset

    floatx4 acc[4];
#pragma unroll
    for (int i = 0; i < 4; i++) acc[i] = (floatx4){0.f, 0.f, 0.f, 0.f};

    uint4 ra = *(const uint4*)pa;
    uint4 rb = *(const uint4*)pb;

    for (int s = 0; s < 25; s++) {
        const int p = s & 1;
        *(uint4*)&As[p][woff] = ra;
        *(uint4*)&Bs[p][woff] = rb;
        __syncthreads();
        if (s + 1 < 25) {
            pa += 32;
            pb += 32;
            ra = *(const uint4*)pa;
            rb = *(const uint4*)pb;
        }
        short8 af = *(const short8*)&As[p][(16 * w + l15) * 64 + ru];
#pragma unroll
        for (int ng = 0; ng < 4; ng++) {
            short8 bf = *(const short8*)&Bs[p][(16 * ng + l15) * 64 + ru];
            acc[ng] = __builtin_amdgcn_mfma_f32_16x16x32_bf16(af, bf, acc[ng], 0, 0, 0);
        }
        __syncthreads();
    }

#pragma unroll
    for (int ng = 0; ng < 4; ng++) {
        int col = ntile * 64 + ng * 16 + l15;
        if (col < 465) {
#pragma unroll
            for (int r = 0; r < 4; r++)
                atomicAdd(&msum[(16 * w + quad * 4 + r) * 512 + col], acc[ng][r]);
        }
    }
}

// ---- Kernel 3: finalize (now trivial reads from Msum): -> Wout, expout ----
__global__ __launch_bounds__(256) void finalize_w_kernel(const float* __restrict__ W,
                                                         const float* __restrict__ msum,
                                                         const float* __restrict__ exp_avg,
                                                         float* __restrict__ Wout,
                                                         float* __restrict__ expout) {
    __shared__ float gfps[OUT_CH];
    __shared__ float ytys[2][OUT_CH];
    const int tid = threadIdx.x;
    const int bid = blockIdx.x;
    const int first_o = (bid * 256) / 400;

    if (tid < OUT_CH) {  // colsum -> exp_new -> gfp
        int o = tid;
        float cs = msum[o * 512 + 464];
        float e = GAMMA_F * exp_avg[o] + ONE_MINUS_GAMMA * (cs / (float)NB_TILES);
        float s = e;
        for (int off = 32; off; off >>= 1) s += __shfl_down(s, off);
        s = __shfl(s, 0);
        float A = e / (s / (float)OUT_CH);
        gfps[o] = EPS_F * tanhf(-EPS_F * (A - 1.f)) + 1.f;
        if (bid == 0) expout[o] = e;
    }
    if (tid >= 128) {  // the <=2 yty rows this block needs
        int t = tid - 128;
        int orow = first_o + (t >> 6);
        int k = t & 63;
        float s = (orow < OUT_CH) ? msum[orow * 512 + 400 + k] : 0.f;
        ytys[t >> 6][k] = s;
    }
    __syncthreads();

    int idx = bid * 256 + tid;
    int o = idx / 400;
    int q = idx - o * 400;
    float Mv = msum[o * 512 + q];
    const float* yrow = ytys[o - first_o];
    float dot = 0.f;
#pragma unroll 8
    for (int k = 0; k < OUT_CH; k++) dot = fmaf(yrow[k], W[k * 400 + q], dot);
    float wv = W[idx] + LR_OVER_NB * (Mv - dot);
    wv = fmaxf(wv, 0.f);
    float gp = gfps[o];
    float pos = (wv > 0.f ? wv : 0.f) * gp;
    float neg = (wv < 0.f ? wv : 0.f) / gp;
    Wout[idx] = pos + neg;
}

extern "C" void kernel_launch(void* const* d_in, const int* in_sizes, int n_in,
                              void* d_out, int out_size, void* d_ws, size_t ws_size,
                              hipStream_t stream) {
    const float* x = (const float*)d_in[0];
    const float* W = (const float*)d_in[1];
    const float* exp_avg = (const float*)d_in[2];
    float* out = (float*)d_out;

    float* wsf = (float*)d_ws;
    float* msum = wsf + 29760;                  // 64*512 floats (zeroed by prepB)
    uint16_t* ybf = (uint16_t*)(wsf + 29760 + NCHUNK * PSTRIDE);  // 64*51200 bf16
    uint16_t* xsb = ybf + OUT_CH * KP2;                            // 5*16*52224 bf16
    uint16_t* ones = xsb + 5 * 16 * XS;                            // 51264 bf16

    float* Wout = out + OUT_CH * OUT_PLANE;
    float* expout = Wout + OUT_CH * IN_CH * KER * KER;

    conv_prep_kernel<<<770 + 2040, 256, 0, stream>>>(W, out, ybf, x, xsb, ones, msum);
    gemm_kernel<<<512, 256, 0, stream>>>(ybf, xsb, ones, msum);
    finalize_w_kernel<<<100, 256, 0, stream>>>(W, msum, exp_avg, Wout, expout);
}

// Round 7
// 108.938 us; speedup vs baseline: 1.3215x; 1.3215x over previous
//
#include <hip/hip_runtime.h>
#include <stdint.h>

#define IN_SIZE 224
#define KER 5
#define IN_CH 16
#define OUT_CH 64
#define NH 220
#define NB_TILES (NH * NH)       // 48400
#define XCH (IN_SIZE * IN_SIZE)  // 50176
#define OUT_PLANE NB_TILES
#define KP2 51200                // padded K for gemm
#define XS 52224                 // per-plane stride in shifted-x copies
#define LR_OVER_NB ((float)(0.005 / 48400.0))
#define GAMMA_F 0.99f
#define ONE_MINUS_GAMMA 0.01f
#define EPS_F 0.01f

#define NCHUNK 64
#define CK 800                   // 25 steps of BK=32
#define PSTRIDE (64 * 512)

typedef __attribute__((ext_vector_type(8))) short short8;
typedef __attribute__((ext_vector_type(4))) float floatx4;

__device__ inline uint16_t f2bf(float f) {
    uint32_t u = __float_as_uint(f);
    return (uint16_t)((u + 0x7FFFu + ((u >> 16) & 1u)) >> 16);
}
__device__ inline float bf2f(uint16_t h) { return __uint_as_float((uint32_t)h << 16); }

// ---- Kernel 0: prepA: W fragment-packed repack (coalesced table build;
// round-6 proved per-thread scalar W loads in conv are 34 us slower) ----
__global__ __launch_bounds__(256) void prepa_kernel(const float* __restrict__ W,
                                                    uint16_t* __restrict__ wrh,
                                                    uint16_t* __restrict__ wrl) {
    int idx = blockIdx.x * 256 + threadIdx.x;
    if (idx >= 13 * 4 * 64 * 8) return;
    int j = idx & 7;
    int lane = (idx >> 3) & 63;
    int ocg = (idx >> 9) & 3;
    int t = idx >> 11;
    int k = (lane >> 4) * 8 + j;
    int s = k >> 4, c = k & 15;
    int oc = 16 * ocg + (lane & 15);
    int tap = 2 * t + s;
    float v = (tap < 25) ? W[oc * 400 + c * 25 + tap] : 0.f;
    uint16_t h = f2bf(v);
    wrh[idx] = h;
    wrl[idx] = f2bf(v - bf2f(h));
}

// ---- Kernel 1: conv MFMA (B staged from x directly, hi/lo split in-kernel,
// XOR-swizzled LDS) + inhibition; prepB fused (16B-vectorized xs builder).
// blocks 0..769: conv; blocks 770..2809: prepB (independent memory work) ----
__global__ __launch_bounds__(256) void conv_prep_kernel(const uint16_t* __restrict__ wrh,
                                                        const uint16_t* __restrict__ wrl,
                                                        float* __restrict__ out,
                                                        uint16_t* __restrict__ yb,
                                                        const float* __restrict__ x,
                                                        uint16_t* __restrict__ xs,
                                                        uint16_t* __restrict__ ones,
                                                        float* __restrict__ msum) {
    if (blockIdx.x >= 770) {  // ---- prepB ----
        int t = (blockIdx.x - 770) * 256 + threadIdx.x;
        const int perq8 = XS / 8;  // 6528
        // xs shifted-copy build, 8 bf16 (16 B) per thread: t covers 5*16*6528 = 522240 exactly
        {
            int kj = t / (16 * perq8);
            int rem = t - kj * (16 * perq8);
            int c = rem / perq8;
            int q = (rem - c * perq8) * 8;
            int base = c * XCH;
            uint32_t d[4];
#pragma unroll
            for (int p = 0; p < 4; p++) {
                int i0 = q + kj + 2 * p;
                int i1 = i0 + 1;
                uint16_t h0 = f2bf(x[base + (i0 < XCH ? i0 : XCH - 1)]);
                uint16_t h1 = f2bf(x[base + (i1 < XCH ? i1 : XCH - 1)]);
                d[p] = (uint32_t)h0 | ((uint32_t)h1 << 16);
            }
            *(uint4*)(xs + (kj * 16 + c) * XS + q) = make_uint4(d[0], d[1], d[2], d[3]);
        }
        ushort4 z = {0, 0, 0, 0};
        if (t < 64 * 480) {  // zero yb K-tail [49280,51200)
            int r = t / 480, q = (t - r * 480) * 4;
            *(ushort4*)(yb + r * KP2 + 49280 + q) = z;
        }
        if (t < 64 * 220) {  // zero yb j-pad cols 220..223
            int o = t / 220, i = t - o * 220;
            *(ushort4*)(yb + o * KP2 + i * 224 + 220) = z;
        }
        if (t < 12816) {  // bf16 ones (51264 entries)
            ushort4 o1 = {0x3F80, 0x3F80, 0x3F80, 0x3F80};
            ((ushort4*)ones)[t] = o1;
        }
        if (t < 8192) {  // zero Msum (64*512 floats) for gemm's atomic accumulate
            float4 z4 = make_float4(0.f, 0.f, 0.f, 0.f);
            ((float4*)msum)[t] = z4;
        }
        return;
    }

    // ---- conv: stage the block's B-window (5 strips x 68 rows x 16ch, hi+lo)
    // in LDS, built directly from x (fp32 -> bf16 hi/lo here). 16B-unit index
    // u = row*2+half is XOR-swizzled with ((row>>2)&1): rows differing by 4
    // (the old 4-way same-bank set) land in different bank quads -> 2-way (free).
    const int lane = threadIdx.x & 63;
    const int w = threadIdx.x >> 6;
    const int l15 = lane & 15;
    const int quad = lane >> 4;
    const int P0 = blockIdx.x * 64;
    const int chalf = quad & 1;   // which 8-channel half this quad reads
    const int sq = quad >> 1;

    __shared__ uint16_t bsh[5 * 68 * 16];  // 10.9 KB
    __shared__ uint16_t bsl[5 * 68 * 16];  // 10.9 KB
    for (int u = threadIdx.x; u < 680; u += 256) {
        int row = u >> 1;            // 0..339
        int half = u & 1;            // channel half 0/1
        int strip = row / 68;
        int rr = row - strip * 68;
        int grow = P0 + strip * 224 + rr;  // may overhang past XCH on last blocks
        bool inb = grow < XCH;
        uint32_t dh[4], dl[4];
#pragma unroll
        for (int q = 0; q < 4; q++) {
            float v0 = inb ? x[(half * 8 + 2 * q) * XCH + grow] : 0.f;
            float v1 = inb ? x[(half * 8 + 2 * q + 1) * XCH + grow] : 0.f;
            uint16_t h0 = f2bf(v0), h1 = f2bf(v1);
            uint16_t l0 = f2bf(v0 - bf2f(h0)), l1 = f2bf(v1 - bf2f(h1));
            dh[q] = (uint32_t)h0 | ((uint32_t)h1 << 16);
            dl[q] = (uint32_t)l0 | ((uint32_t)l1 << 16);
        }
        int swz = (u ^ ((row >> 2) & 1)) * 8;  // swizzled elem offset
        *(uint4*)(bsh + swz) = make_uint4(dh[0], dh[1], dh[2], dh[3]);
        *(uint4*)(bsl + swz) = make_uint4(dl[0], dl[1], dl[2], dl[3]);
    }
    __syncthreads();

    floatx4 acc[4];
#pragma unroll
    for (int g = 0; g < 4; g++) acc[g] = (floatx4){0.f, 0.f, 0.f, 0.f};

#pragma unroll
    for (int t = 0; t < 13; t++) {
        short8 ah = *(const short8*)(wrh + ((t * 4 + w) * 64 + lane) * 8);
        short8 al = *(const short8*)(wrl + ((t * 4 + w) * 64 + lane) * 8);
        const int tap0 = 2 * t, tap1 = 2 * t + 1;
        const int ki0 = tap0 / 5, kj0 = tap0 % 5;
        const int ki1 = (tap1 <= 24) ? tap1 / 5 : 0;
        const int kj1 = (tap1 <= 24) ? tap1 % 5 : 0;
        const int strip = sq ? ki1 : ki0;
        const int kjv = sq ? kj1 : kj0;
#pragma unroll
        for (int g = 0; g < 4; g++) {
            int lrow = strip * 68 + 16 * g + l15 + kjv;
            int unit = lrow * 2 + chalf;
            int off = (unit ^ ((lrow >> 2) & 1)) * 8;
            short8 bh = *(const short8*)(bsh + off);
            short8 bl = *(const short8*)(bsl + off);
            acc[g] = __builtin_amdgcn_mfma_f32_16x16x32_bf16(ah, bh, acc[g], 0, 0, 0);
            acc[g] = __builtin_amdgcn_mfma_f32_16x16x32_bf16(ah, bl, acc[g], 0, 0, 0);
            acc[g] = __builtin_amdgcn_mfma_f32_16x16x32_bf16(al, bh, acc[g], 0, 0, 0);
        }
    }

    __shared__ float wmax[4][64];
    float pmax[4];
#pragma unroll
    for (int g = 0; g < 4; g++) {
        float mx = fmaxf(fmaxf(acc[g][0], acc[g][1]), fmaxf(acc[g][2], acc[g][3]));
        mx = fmaxf(mx, 0.f);
        mx = fmaxf(mx, __shfl_xor(mx, 16));
        mx = fmaxf(mx, __shfl_xor(mx, 32));
        pmax[g] = mx;
    }
    if (quad == 0) {
#pragma unroll
        for (int g = 0; g < 4; g++) wmax[w][g * 16 + l15] = pmax[g];
    }
    __syncthreads();

#pragma unroll
    for (int g = 0; g < 4; g++) {
        int P = P0 + 16 * g + l15;
        int i = P / 224;
        int j = P - i * 224;
        bool valid = j < NH;
        float mx = fmaxf(fmaxf(wmax[0][g * 16 + l15], wmax[1][g * 16 + l15]),
                         fmaxf(wmax[2][g * 16 + l15], wmax[3][g * 16 + l15]));
        float inv = 1.f / (mx + 1e-9f);
#pragma unroll
        for (int r = 0; r < 4; r++) {
            float tv = fmaxf(acc[g][r], 0.f) * inv;
            float t2 = tv * tv;
            tv = t2 * t2 * tv;
            if (valid) {
                int oc = 16 * w + quad * 4 + r;
                out[oc * OUT_PLANE + i * NH + j] = tv;
                yb[oc * KP2 + P] = f2bf(tv);
            }
        }
    }
}

// ---- Kernel 2: LDS-staged GEMM y^T @ [xf|y|1] (round-3 body); epilogue
// ATOMICALLY accumulates into Msum[64][512] (fp32, device-scope, L2-hot
// 128 KB) instead of storing 8.4 MB Mpart. ----
__global__ __launch_bounds__(256) void gemm_kernel(const uint16_t* __restrict__ yb,
                                                   const uint16_t* __restrict__ xs,
                                                   const uint16_t* __restrict__ ones,
                                                   float* __restrict__ msum) {
    __shared__ uint16_t As[2][64 * 40];
    __shared__ uint16_t Bs[2][64 * 40];
    const int tid = threadIdx.x;
    const int lane = tid & 63;
    const int w = tid >> 6;
    const int l15 = lane & 15;
    const int quad = lane >> 4;
    const int kg = quad * 8;
    const int b = blockIdx.x;
    const int xcd = b & 7;
    const int t8 = b >> 3;
    const int ntile = t8 & 7;
    const int chunk = xcd + 8 * (t8 >> 3);
    const int k0 = chunk * CK;

    const int sr = tid >> 2;
    const int sseg = (tid & 3) * 8;
    const uint16_t* pa = yb + sr * KP2 + k0 + sseg;

    int n_g = ntile * 64 + sr;
    const uint16_t* pbase;
    if (n_g < 400) {
        int c = n_g / 25;
        int r = n_g - 25 * c;
        int ki = r / 5;
        int kj = r - 5 * ki;
        pbase = xs + (kj * 16 + c) * XS + ki * 224;
    } else if (n_g < 464) {
        pbase = yb + (n_g - 400) * KP2;
    } else if (n_g == 464) {
        pbase = ones;
    } else {
        pbase = yb;  // dead column
    }
    const uint16_t* pb = pbase + k0 + sseg;

    floatx4 acc[4];
#pragma unroll
    for (int i = 0; i < 4; i++) acc[i] = (floatx4){0.f, 0.f, 0.f, 0.f};

    uint4 ra = *(const uint4*)pa;
    uint4 rb = *(const uint4*)pb;

    for (int s = 0; s < 25; s++) {
        const int p = s & 1;
        *(uint4*)&As[p][sr * 40 + sseg] = ra;
        *(uint4*)&Bs[p][sr * 40 + sseg] = rb;
        __syncthreads();
        if (s + 1 < 25) {
            pa += 32;
            pb += 32;
            ra = *(const uint4*)pa;
            rb = *(const uint4*)pb;
        }
        short8 af = *(const short8*)&As[p][(16 * w + l15) * 40 + kg];
#pragma unroll
        for (int ng = 0; ng < 4; ng++) {
            short8 bf = *(const short8*)&Bs[p][(16 * ng + l15) * 40 + kg];
            acc[ng] = __builtin_amdgcn_mfma_f32_16x16x32_bf16(af, bf, acc[ng], 0, 0, 0);
        }
        __syncthreads();
    }

#pragma unroll
    for (int ng = 0; ng < 4; ng++) {
        int col = ntile * 64 + ng * 16 + l15;
        if (col < 465) {
#pragma unroll
            for (int r = 0; r < 4; r++)
                atomicAdd(&msum[(16 * w + quad * 4 + r) * 512 + col], acc[ng][r]);
        }
    }
}

// ---- Kernel 3: finalize (trivial reads from Msum): -> Wout, expout ----
__global__ __launch_bounds__(256) void finalize_w_kernel(const float* __restrict__ W,
                                                         const float* __restrict__ msum,
                                                         const float* __restrict__ exp_avg,
                                                         float* __restrict__ Wout,
                                                         float* __restrict__ expout) {
    __shared__ float gfps[OUT_CH];
    __shared__ float ytys[2][OUT_CH];
    const int tid = threadIdx.x;
    const int bid = blockIdx.x;
    const int first_o = (bid * 256) / 400;

    if (tid < OUT_CH) {  // colsum -> exp_new -> gfp
        int o = tid;
        float cs = msum[o * 512 + 464];
        float e = GAMMA_F * exp_avg[o] + ONE_MINUS_GAMMA * (cs / (float)NB_TILES);
        float s = e;
        for (int off = 32; off; off >>= 1) s += __shfl_down(s, off);
        s = __shfl(s, 0);
        float A = e / (s / (float)OUT_CH);
        gfps[o] = EPS_F * tanhf(-EPS_F * (A - 1.f)) + 1.f;
        if (bid == 0) expout[o] = e;
    }
    if (tid >= 128) {  // the <=2 yty rows this block needs
        int t = tid - 128;
        int orow = first_o + (t >> 6);
        int k = t & 63;
        float s = (orow < OUT_CH) ? msum[orow * 512 + 400 + k] : 0.f;
        ytys[t >> 6][k] = s;
    }
    __syncthreads();

    int idx = bid * 256 + tid;
    int o = idx / 400;
    int q = idx - o * 400;
    float Mv = msum[o * 512 + q];
    const float* yrow = ytys[o - first_o];
    float dot = 0.f;
#pragma unroll 8
    for (int k = 0; k < OUT_CH; k++) dot = fmaf(yrow[k], W[k * 400 + q], dot);
    float wv = W[idx] + LR_OVER_NB * (Mv - dot);
    wv = fmaxf(wv, 0.f);
    float gp = gfps[o];
    float pos = (wv > 0.f ? wv : 0.f) * gp;
    float neg = (wv < 0.f ? wv : 0.f) / gp;
    Wout[idx] = pos + neg;
}

extern "C" void kernel_launch(void* const* d_in, const int* in_sizes, int n_in,
                              void* d_out, int out_size, void* d_ws, size_t ws_size,
                              hipStream_t stream) {
    const float* x = (const float*)d_in[0];
    const float* W = (const float*)d_in[1];
    const float* exp_avg = (const float*)d_in[2];
    float* out = (float*)d_out;

    float* wsf = (float*)d_ws;
    float* msum = wsf + 29760;                  // 64*512 floats (zeroed by prepB)
    uint16_t* wrh = (uint16_t*)(wsf + 29760 + 64 * 512);  // 26624 (after msum: no
    uint16_t* wrl = wrh + 26624;                           //  race with msum zeroing)
    uint16_t* ybf = (uint16_t*)(wsf + 29760 + NCHUNK * PSTRIDE);  // 64*51200 bf16
    uint16_t* xsb = ybf + OUT_CH * KP2;                            // 5*16*52224 bf16
    uint16_t* ones = xsb + 5 * 16 * XS;                            // 51264 bf16

    float* Wout = out + OUT_CH * OUT_PLANE;
    float* expout = Wout + OUT_CH * IN_CH * KER * KER;

    prepa_kernel<<<104, 256, 0, stream>>>(W, wrh, wrl);
    conv_prep_kernel<<<770 + 2040, 256, 0, stream>>>(wrh, wrl, out, ybf, x, xsb, ones, msum);
    gemm_kernel<<<512, 256, 0, stream>>>(ybf, xsb, ones, msum);
    finalize_w_kernel<<<100, 256, 0, stream>>>(W, msum, exp_avg, Wout, expout);
}